// Round 4
// baseline (157.272 us; speedup 1.0000x reference)
//
#include <hip/hip_runtime.h>
#include <hip/hip_bf16.h>

#define HH 1024
#define LL 512

typedef __attribute__((ext_vector_type(8))) short bf16x8;
typedef __attribute__((ext_vector_type(4))) float f32x4;

static constexpr float C_EXP = 2.8853900817779268f; // 2*log2(e)

// pack 8 fp32 -> 8 bf16 (RNE) as uint4, element order preserved
static __device__ __forceinline__ uint4 pack8(float4 a, float4 b) {
    union { uint4 u; __hip_bfloat162 h[4]; } r;
    r.h[0] = __float22bfloat162_rn(make_float2(a.x, a.y));
    r.h[1] = __float22bfloat162_rn(make_float2(a.z, a.w));
    r.h[2] = __float22bfloat162_rn(make_float2(b.x, b.y));
    r.h[3] = __float22bfloat162_rn(make_float2(b.z, b.w));
    return r.u;
}

// ---------------------------------------------------------------------------
// Kernel 1: bf16 MFMA projection, fp32->bf16 convert fused into staging.
//   acc[m][n] = sum_k lm[m,k] * Wrow[n,k],  Wrow[n,k] = W1[(n&1023)*2048 + (n>>10)*1024 + k]
//   n < 1024:  Ea[m][n]      = exp2(C*(acc + b1[n]))
//   n >= 1024: Eb[m][n-1024] = exp2(C*acc)
// Block tile 32m x 64n, 4 waves each 16m x 32n, BK=64. Grid (32,16)=512.
// ---------------------------------------------------------------------------
__global__ __launch_bounds__(256) void proj_mfma_kernel(
    const float* __restrict__ lm, const float* __restrict__ W1,
    const float* __restrict__ b1, float* __restrict__ Ea, float* __restrict__ Eb)
{
    __shared__ ushort As[32][72];   // rows padded to 72 bf16: all patterns <=2-way
    __shared__ ushort Bs[64][72];

    const int tid  = threadIdx.x;
    const int lane = tid & 63;
    const int w    = tid >> 6;
    const int mbase = blockIdx.y * 32;
    const int nbase = blockIdx.x * 64;
    const int wm = (w & 1) * 16;
    const int wn = (w >> 1) * 32;

    const int sel  = nbase >> 10;     // uniform: Wa (0) or Wb (1) half
    const int nrow = nbase & 1023;

    f32x4 acc0 = {0.f, 0.f, 0.f, 0.f};
    f32x4 acc1 = {0.f, 0.f, 0.f, 0.f};

    const int srow = tid >> 3;        // 0..31
    const int sc8  = (tid & 7) * 8;   // bf16 col, 8-elem groups

    const int mrow = lane & 15;
    const int q8   = (lane >> 4) * 8;

    for (int kb = 0; kb < HH; kb += 64) {
        __syncthreads();
        {
            const float* pa = &lm[(mbase + srow) * HH + kb + sc8];
            *(uint4*)&As[srow][sc8] = pack8(*(const float4*)pa, *(const float4*)(pa + 4));
            const float* pb0 = &W1[(nrow + srow) * 2048 + sel * 1024 + kb + sc8];
            *(uint4*)&Bs[srow][sc8] = pack8(*(const float4*)pb0, *(const float4*)(pb0 + 4));
            const float* pb1 = &W1[(nrow + srow + 32) * 2048 + sel * 1024 + kb + sc8];
            *(uint4*)&Bs[srow + 32][sc8] = pack8(*(const float4*)pb1, *(const float4*)(pb1 + 4));
        }
        __syncthreads();

#pragma unroll
        for (int s = 0; s < 2; ++s) {
            const bf16x8 a  = *(const bf16x8*)&As[wm + mrow][s * 32 + q8];
            const bf16x8 b0 = *(const bf16x8*)&Bs[wn + mrow][s * 32 + q8];
            const bf16x8 bf = *(const bf16x8*)&Bs[wn + 16 + mrow][s * 32 + q8];
            acc0 = __builtin_amdgcn_mfma_f32_16x16x32_bf16(a, b0, acc0, 0, 0, 0);
            acc1 = __builtin_amdgcn_mfma_f32_16x16x32_bf16(a, bf, acc1, 0, 0, 0);
        }
    }

    // D mapping: col=lane&15 (n), row=(lane>>4)*4+reg (m)
    const int col = lane & 15;
    const int rq  = (lane >> 4) * 4;
#pragma unroll
    for (int t = 0; t < 2; ++t) {
        const f32x4 acc = t ? acc1 : acc0;
        const int n_g = nbase + wn + t * 16 + col;
        const int m0  = mbase + wm + rq;
        if (n_g < HH) {
            const float bb = b1[n_g];
#pragma unroll
            for (int r = 0; r < 4; ++r)
                Ea[(m0 + r) * HH + n_g] = __builtin_amdgcn_exp2f(C_EXP * (acc[r] + bb));
        } else {
#pragma unroll
            for (int r = 0; r < 4; ++r)
                Eb[(m0 + r) * HH + (n_g - HH)] = __builtin_amdgcn_exp2f(C_EXP * acc[r]);
        }
    }
}

// ---------------------------------------------------------------------------
// Kernel 2: pairwise contraction, exp-form, batched rcp (1 per 4 outputs),
// h split 4-ways for occupancy, symmetrization fused via 0.5x atomics to
// both (i,j) and (j,i). out must be pre-zeroed.
//   t(i,j,h) = 1 - 2/(Ea[j,h]*Eb[i,h] + 1)
//   logits_presym(i,j,c) = sum_h t*W2[c,h] + b2[c]
//                        = sum_h W2[c,h]  +  sum_h r*w'  + b2[c],  w' = -2*W2, r = 1/(ea*eb+1)
// Tile 32i x 32j x 256h per block; thread owns {ty,ty+16} x {tx,tx+16}.
// Grid (16,16,4) = 1024 blocks = 4 blocks/CU.
// ---------------------------------------------------------------------------
__global__ __launch_bounds__(256, 4) void pair_kernel(
    const float* __restrict__ Ea, const float* __restrict__ Eb,
    const float* __restrict__ W2, const float* __restrict__ b2,
    float* __restrict__ out)
{
    __shared__ float a_s[32][132];   // stride 132 = 4 mod 32 banks: <=2-way, free
    __shared__ float b_s[32][132];
    __shared__ float w0_s[256], w1_s[256];
    __shared__ float s_red[2];

    const int tid   = threadIdx.x;
    const int tx    = tid & 15;
    const int ty    = tid >> 4;
    const int jbase = blockIdx.x * 32;
    const int ibase = blockIdx.y * 32;
    const int k0    = blockIdx.z * 256;

    // stage w' = -2*W2 slice (wave 0: c=0, wave 1: c=1 -> wave-coherent reduce)
    if (tid < 128) {
        const int c = tid >> 6, q = tid & 63;
        const float4 v = *(const float4*)&W2[c * HH + k0 + q * 4];
        ((float4*)(c ? w1_s : w0_s))[q] =
            make_float4(-2.f * v.x, -2.f * v.y, -2.f * v.z, -2.f * v.w);
    }
    if (tid < 128) {
        const int c = tid >> 6, l = tid & 63;
        const float* ws = c ? w1_s : w0_s;
        float s = ws[l] + ws[l + 64] + ws[l + 128] + ws[l + 192];
#pragma unroll
        for (int off = 32; off; off >>= 1) s += __shfl_down(s, off, 64);
        if (l == 0) s_red[c] = s;
    }

    float acc[2][2][2] = {}; // [i-half][j-half][c]

    for (int kb = 0; kb < 256; kb += 128) {
        __syncthreads();
        int p = tid;
#pragma unroll
        for (int it = 0; it < 8; ++it, p += 256) {
            const int row = p >> 5;   // 0..63
            const int c4  = p & 31;
            if (row < 32)
                *(float4*)&a_s[row][c4 * 4] =
                    *(const float4*)&Ea[(jbase + row) * HH + k0 + kb + c4 * 4];
            else
                *(float4*)&b_s[row - 32][c4 * 4] =
                    *(const float4*)&Eb[(ibase + row - 32) * HH + k0 + kb + c4 * 4];
        }
        __syncthreads();

#pragma unroll 4
        for (int h4 = 0; h4 < 32; ++h4) {
            const float4 ea0 = *(const float4*)&a_s[tx][h4 * 4];
            const float4 ea1 = *(const float4*)&a_s[tx + 16][h4 * 4];
            const float4 eb0 = *(const float4*)&b_s[ty][h4 * 4];
            const float4 eb1 = *(const float4*)&b_s[ty + 16][h4 * 4];
            const float4 w0  = *(const float4*)&w0_s[kb + h4 * 4]; // broadcast
            const float4 w1  = *(const float4*)&w1_s[kb + h4 * 4];

#define DO_H(EA0, EA1, EB0, EB1, W0V, W1V)                            \
            {                                                         \
                const float d00 = __builtin_fmaf((EB0), (EA0), 1.f);  \
                const float d01 = __builtin_fmaf((EB0), (EA1), 1.f);  \
                const float d10 = __builtin_fmaf((EB1), (EA0), 1.f);  \
                const float d11 = __builtin_fmaf((EB1), (EA1), 1.f);  \
                const float p0 = d00 * d01, p1 = d10 * d11;           \
                const float R  = __builtin_amdgcn_rcpf(p0 * p1);      \
                const float q0 = R * p1, q1 = R * p0;                 \
                const float r00 = q0 * d01, r01 = q0 * d00;           \
                const float r10 = q1 * d11, r11 = q1 * d10;           \
                acc[0][0][0] = __builtin_fmaf(r00, (W0V), acc[0][0][0]); \
                acc[0][0][1] = __builtin_fmaf(r00, (W1V), acc[0][0][1]); \
                acc[0][1][0] = __builtin_fmaf(r01, (W0V), acc[0][1][0]); \
                acc[0][1][1] = __builtin_fmaf(r01, (W1V), acc[0][1][1]); \
                acc[1][0][0] = __builtin_fmaf(r10, (W0V), acc[1][0][0]); \
                acc[1][0][1] = __builtin_fmaf(r10, (W1V), acc[1][0][1]); \
                acc[1][1][0] = __builtin_fmaf(r11, (W0V), acc[1][1][0]); \
                acc[1][1][1] = __builtin_fmaf(r11, (W1V), acc[1][1][1]); \
            }
            DO_H(ea0.x, ea1.x, eb0.x, eb1.x, w0.x, w1.x)
            DO_H(ea0.y, ea1.y, eb0.y, eb1.y, w0.y, w1.y)
            DO_H(ea0.z, ea1.z, eb0.z, eb1.z, w0.z, w1.z)
            DO_H(ea0.w, ea1.w, eb0.w, eb1.w, w0.w, w1.w)
#undef DO_H
        }
    }

    // epilogue: val = 0.5*(P_slice) + [ks==0]*0.5*b2;  P_slice = acc - 0.5*s'
    const float sc0 = -0.25f * s_red[0];
    const float sc1 = -0.25f * s_red[1];
    const float bb0 = (blockIdx.z == 0) ? 0.5f * b2[0] : 0.f;
    const float bb1 = (blockIdx.z == 0) ? 0.5f * b2[1] : 0.f;

#pragma unroll
    for (int ii = 0; ii < 2; ++ii) {
#pragma unroll
        for (int jj = 0; jj < 2; ++jj) {
            const int i = ibase + ty + ii * 16;
            const int j = jbase + tx + jj * 16;
            const float v0 = 0.5f * acc[ii][jj][0] + sc0 + bb0;
            const float v1 = 0.5f * acc[ii][jj][1] + sc1 + bb1;
            atomicAdd(&out[(i * LL + j) * 2 + 0], v0);
            atomicAdd(&out[(i * LL + j) * 2 + 1], v1);
            atomicAdd(&out[(j * LL + i) * 2 + 0], v0);
            atomicAdd(&out[(j * LL + i) * 2 + 1], v1);
        }
    }
}

extern "C" void kernel_launch(void* const* d_in, const int* in_sizes, int n_in,
                              void* d_out, int out_size, void* d_ws, size_t ws_size,
                              hipStream_t stream)
{
    const float* lm = (const float*)d_in[0];
    const float* W1 = (const float*)d_in[1];
    const float* b1 = (const float*)d_in[2];
    const float* W2 = (const float*)d_in[3];
    const float* b2 = (const float*)d_in[4];
    float* out = (float*)d_out;

    float* Ea = (float*)d_ws;                  // 2 MB
    float* Eb = Ea + (size_t)LL * HH;          // 2 MB

    hipMemsetAsync(d_out, 0, (size_t)LL * LL * 2 * sizeof(float), stream);
    proj_mfma_kernel<<<dim3(32, 16), 256, 0, stream>>>(lm, W1, b1, Ea, Eb);
    pair_kernel<<<dim3(16, 16, 4), 256, 0, stream>>>(Ea, Eb, W2, b2, out);
}

// Round 5
// 137.058 us; speedup vs baseline: 1.1475x; 1.1475x over previous
//
#include <hip/hip_runtime.h>
#include <hip/hip_bf16.h>

#define HH 1024
#define LL 512
#define NT 16              // 512/32 row-tiles
#define NTRI 136           // NT*(NT+1)/2 triangular tiles

typedef __attribute__((ext_vector_type(8))) short bf16x8;
typedef __attribute__((ext_vector_type(4))) float f32x4;

static constexpr float C_EXP = 2.8853900817779268f; // 2*log2(e)

// pack 8 fp32 -> 8 bf16 (RNE) as uint4, element order preserved
static __device__ __forceinline__ uint4 pack8(float4 a, float4 b) {
    union { uint4 u; __hip_bfloat162 h[4]; } r;
    r.h[0] = __float22bfloat162_rn(make_float2(a.x, a.y));
    r.h[1] = __float22bfloat162_rn(make_float2(a.z, a.w));
    r.h[2] = __float22bfloat162_rn(make_float2(b.x, b.y));
    r.h[3] = __float22bfloat162_rn(make_float2(b.z, b.w));
    return r.u;
}

// ---------------------------------------------------------------------------
// Kernel 1: bf16 MFMA projection, fp32->bf16 fused into staging.
//   acc[m][n] = sum_k lm[m,k] * Wrow[n,k],
//     Wrow[n,k] = W1[(n&1023)*2048 + (n>>10)*1024 + k]
//   n < 1024:  Ea[m][n]      = exp2(C*(acc + b1[n]))
//   n >= 1024: Eb[m][n-1024] = exp2(C*acc)
// Tile 16m x 64n, BK=128, 4 waves each own one 16x16 n-strip.
// Grid (2048/64, 512/16) = (32,32) = 1024 blocks = 4/CU (vs round-4's 2/CU).
// ---------------------------------------------------------------------------
__global__ __launch_bounds__(256, 4) void proj_mfma_kernel(
    const float* __restrict__ lm, const float* __restrict__ W1,
    const float* __restrict__ b1, float* __restrict__ Ea, float* __restrict__ Eb)
{
    __shared__ ushort As[16][136];  // 136 ushort = 68 dw = 4 mod 32: <=2-way, free
    __shared__ ushort Bs[64][136];

    const int tid  = threadIdx.x;
    const int lane = tid & 63;
    const int w    = tid >> 6;
    const int mbase = blockIdx.y * 16;
    const int nbase = blockIdx.x * 64;
    const int sel  = nbase >> 10;     // uniform per block: Wa(0) / Wb(1)
    const int nrow = nbase & 1023;
    const int wn   = w * 16;

    const int mrow = lane & 15;
    const int q8   = (lane >> 4) * 8;

    f32x4 acc = {0.f, 0.f, 0.f, 0.f};

    for (int kb = 0; kb < HH; kb += 128) {
        __syncthreads();
        {   // As: 16x128 bf16 = 256 pack8 slots, 1/thread
            const int row = tid >> 4, c8 = (tid & 15) * 8;
            const float* pa = &lm[(mbase + row) * HH + kb + c8];
            *(uint4*)&As[row][c8] = pack8(*(const float4*)pa, *(const float4*)(pa + 4));
            // Bs: 64x128 bf16 = 1024 slots, 4/thread
            int p = tid;
#pragma unroll
            for (int it = 0; it < 4; ++it, p += 256) {
                const int br = p >> 4, bc8 = (p & 15) * 8;
                const float* pb = &W1[(nrow + br) * 2048 + sel * 1024 + kb + bc8];
                *(uint4*)&Bs[br][bc8] = pack8(*(const float4*)pb, *(const float4*)(pb + 4));
            }
        }
        __syncthreads();

#pragma unroll
        for (int s = 0; s < 4; ++s) {
            const bf16x8 a = *(const bf16x8*)&As[mrow][s * 32 + q8];
            const bf16x8 b = *(const bf16x8*)&Bs[wn + mrow][s * 32 + q8];
            acc = __builtin_amdgcn_mfma_f32_16x16x32_bf16(a, b, acc, 0, 0, 0);
        }
    }

    // D mapping: col=lane&15 (n within strip), row=(lane>>4)*4+reg (m)
    const int col = lane & 15;
    const int rq  = (lane >> 4) * 4;
    const int n_g = nbase + wn + col;
    const int m0  = mbase + rq;
    if (n_g < HH) {                          // uniform per block
        const float bb = b1[n_g];
#pragma unroll
        for (int r = 0; r < 4; ++r)
            Ea[(m0 + r) * HH + n_g] = __builtin_amdgcn_exp2f(C_EXP * (acc[r] + bb));
    } else {
#pragma unroll
        for (int r = 0; r < 4; ++r)
            Eb[(m0 + r) * HH + (n_g - HH)] = __builtin_amdgcn_exp2f(C_EXP * acc[r]);
    }
}

// ---------------------------------------------------------------------------
// Kernel 2: triangular pairwise contraction, symmetrization fused in-register.
//   r_ij = 1/(Ea[j,h]*Eb[i,h]+1), r_ji = 1/(Ea[i,h]*Eb[j,h]+1)
//   S_slice(i,j,c) = sum_slice W2[c,h] + 0.5*sum_h w'(r_ij+r_ji), w' = -2*W2
// Block = one (bi<=bj) 32x32 tile pair x one h-slice. Thread owns 2i x 2j.
// Plain stores to pbuf[(z*NTRI+t)*2048 + (li*32+lj)*2 + c]. No atomics.
// Grid (NTRI, nz). nz=8 -> 1088 blocks ~ 4/CU; LDS ~36 KB -> 4 blocks/CU.
// ---------------------------------------------------------------------------
__global__ __launch_bounds__(256, 4) void pair_kernel(
    const float* __restrict__ Ea, const float* __restrict__ Eb,
    const float* __restrict__ W2, float* __restrict__ pbuf, int nz)
{
    __shared__ float eaj[32][68];   // stride 68 = 4 mod 32 banks: <=2-way, free
    __shared__ float eai[32][68];
    __shared__ float ebi[32][68];
    __shared__ float ebj[32][68];
    __shared__ float w0_s[256], w1_s[256];
    __shared__ float s_red[2];

    const int tid = threadIdx.x;
    const int tx  = tid & 15;
    const int ty  = tid >> 4;

    // decode triangular tile index -> (bi, bj), bi <= bj  (uniform scalar loop)
    int tt = blockIdx.x, bi = 0, rem = NT;
    while (tt >= rem) { tt -= rem; --rem; ++bi; }
    const int bj    = bi + tt;
    const int ibase = bi * 32;
    const int jbase = bj * 32;
    const int slice = HH / nz;
    const int k0    = blockIdx.y * slice;

    // stage w' = -2*W2 slice; wave0 handles c=0, wave1 c=1 (same-wave LDS RAW ok)
    if (tid < 128) {
        const int c = tid >> 6, l = tid & 63;
        float* ws = c ? w1_s : w0_s;
        float s = 0.f;
        for (int q = l; q < slice / 4; q += 64) {
            const float4 v = *(const float4*)&W2[c * HH + k0 + q * 4];
            const float4 nv = make_float4(-2.f * v.x, -2.f * v.y, -2.f * v.z, -2.f * v.w);
            ((float4*)ws)[q] = nv;
            s += nv.x + nv.y + nv.z + nv.w;
        }
#pragma unroll
        for (int off = 32; off; off >>= 1) s += __shfl_down(s, off, 64);
        if (l == 0) s_red[c] = -0.5f * s;   // = sum_slice W2[c,h]
    }

    float acc[2][2][2] = {};  // [ii][jj][c]

    for (int kb = 0; kb < slice; kb += 64) {
        __syncthreads();
        {   // stage 4 tiles x 32 rows x 64 floats = 2048 float4, 8/thread
            int p = tid;
#pragma unroll
            for (int it = 0; it < 8; ++it, p += 256) {
                const int tile = p >> 9;          // compile-time per it
                const int row  = (p >> 4) & 31;
                const int c4   = p & 15;
                float4 v;
                if      (tile == 0) v = *(const float4*)&Ea[(jbase + row) * HH + k0 + kb + c4 * 4];
                else if (tile == 1) v = *(const float4*)&Ea[(ibase + row) * HH + k0 + kb + c4 * 4];
                else if (tile == 2) v = *(const float4*)&Eb[(ibase + row) * HH + k0 + kb + c4 * 4];
                else                v = *(const float4*)&Eb[(jbase + row) * HH + k0 + kb + c4 * 4];
                if      (tile == 0) *(float4*)&eaj[row][c4 * 4] = v;
                else if (tile == 1) *(float4*)&eai[row][c4 * 4] = v;
                else if (tile == 2) *(float4*)&ebi[row][c4 * 4] = v;
                else                *(float4*)&ebj[row][c4 * 4] = v;
            }
        }
        __syncthreads();

#pragma unroll 4
        for (int h4 = 0; h4 < 16; ++h4) {
            const float4 Aj0 = *(const float4*)&eaj[tx][h4 * 4];
            const float4 Aj1 = *(const float4*)&eaj[tx + 16][h4 * 4];
            const float4 Bi0 = *(const float4*)&ebi[ty][h4 * 4];
            const float4 Bi1 = *(const float4*)&ebi[ty + 16][h4 * 4];
            const float4 Ai0 = *(const float4*)&eai[ty][h4 * 4];
            const float4 Ai1 = *(const float4*)&eai[ty + 16][h4 * 4];
            const float4 Bj0 = *(const float4*)&ebj[tx][h4 * 4];
            const float4 Bj1 = *(const float4*)&ebj[tx + 16][h4 * 4];
            const float4 w0  = *(const float4*)&w0_s[kb + h4 * 4];  // broadcast
            const float4 w1  = *(const float4*)&w1_s[kb + h4 * 4];

#define DO_H(AJ0, AJ1, BI0, BI1, AI0, AI1, BJ0, BJ1, W0V, W1V)        \
            {                                                          \
                const float d00 = __builtin_fmaf((BI0), (AJ0), 1.f);   \
                const float d01 = __builtin_fmaf((BI0), (AJ1), 1.f);   \
                const float d10 = __builtin_fmaf((BI1), (AJ0), 1.f);   \
                const float d11 = __builtin_fmaf((BI1), (AJ1), 1.f);   \
                const float e00 = __builtin_fmaf((AI0), (BJ0), 1.f);   \
                const float e01 = __builtin_fmaf((AI0), (BJ1), 1.f);   \
                const float e10 = __builtin_fmaf((AI1), (BJ0), 1.f);   \
                const float e11 = __builtin_fmaf((AI1), (BJ1), 1.f);   \
                const float dp0 = d00 * d01, dp1 = d10 * d11;          \
                const float DR  = __builtin_amdgcn_rcpf(dp0 * dp1);    \
                const float dq0 = DR * dp1, dq1 = DR * dp0;            \
                const float rd00 = dq0 * d01, rd01 = dq0 * d00;        \
                const float rd10 = dq1 * d11, rd11 = dq1 * d10;        \
                const float ep0 = e00 * e01, ep1 = e10 * e11;          \
                const float ER  = __builtin_amdgcn_rcpf(ep0 * ep1);    \
                const float eq0 = ER * ep1, eq1 = ER * ep0;            \
                const float re00 = eq0 * e01, re01 = eq0 * e00;        \
                const float re10 = eq1 * e11, re11 = eq1 * e10;        \
                const float u00 = rd00 + re00, u01 = rd01 + re01;      \
                const float u10 = rd10 + re10, u11 = rd11 + re11;      \
                acc[0][0][0] = __builtin_fmaf(u00, (W0V), acc[0][0][0]); \
                acc[0][0][1] = __builtin_fmaf(u00, (W1V), acc[0][0][1]); \
                acc[0][1][0] = __builtin_fmaf(u01, (W0V), acc[0][1][0]); \
                acc[0][1][1] = __builtin_fmaf(u01, (W1V), acc[0][1][1]); \
                acc[1][0][0] = __builtin_fmaf(u10, (W0V), acc[1][0][0]); \
                acc[1][0][1] = __builtin_fmaf(u10, (W1V), acc[1][0][1]); \
                acc[1][1][0] = __builtin_fmaf(u11, (W0V), acc[1][1][0]); \
                acc[1][1][1] = __builtin_fmaf(u11, (W1V), acc[1][1][1]); \
            }
            DO_H(Aj0.x, Aj1.x, Bi0.x, Bi1.x, Ai0.x, Ai1.x, Bj0.x, Bj1.x, w0.x, w1.x)
            DO_H(Aj0.y, Aj1.y, Bi0.y, Bi1.y, Ai0.y, Ai1.y, Bj0.y, Bj1.y, w0.y, w1.y)
            DO_H(Aj0.z, Aj1.z, Bi0.z, Bi1.z, Ai0.z, Ai1.z, Bj0.z, Bj1.z, w0.z, w1.z)
            DO_H(Aj0.w, Aj1.w, Bi0.w, Bi1.w, Ai0.w, Ai1.w, Bj0.w, Bj1.w, w0.w, w1.w)
#undef DO_H
        }
    }

    // epilogue: S_slice = sum_slice(W2) + 0.5*acc ; plain stores, no atomics
    const float s0 = s_red[0];
    const float s1 = s_red[1];
    float* pb = pbuf + ((size_t)blockIdx.y * NTRI + blockIdx.x) * 2048;
#pragma unroll
    for (int ii = 0; ii < 2; ++ii) {
#pragma unroll
        for (int jj = 0; jj < 2; ++jj) {
            const int li = ty + ii * 16, lj = tx + jj * 16;
            float2* dst = (float2*)&pb[(li * 32 + lj) * 2];
            *dst = make_float2(0.5f * acc[ii][jj][0] + s0,
                               0.5f * acc[ii][jj][1] + s1);
        }
    }
}

// ---------------------------------------------------------------------------
// Kernel 3: combine nz slice-partials, add b2, scatter to (i,j) and (j,i).
// 136*2048 elems / 256 = 1088 blocks. ~11 MB traffic, L2-resident, ~4 us.
// ---------------------------------------------------------------------------
__global__ __launch_bounds__(256) void combine_kernel(
    const float* __restrict__ pbuf, const float* __restrict__ b2,
    float* __restrict__ out, int nz)
{
    const int idx   = blockIdx.x * 256 + threadIdx.x;   // 0 .. 136*2048-1
    const int t     = idx >> 11;
    const int local = idx & 2047;
    int tt = t, bi = 0, rem = NT;
    while (tt >= rem) { tt -= rem; --rem; ++bi; }
    const int bj = bi + tt;

    float s = 0.f;
    for (int z = 0; z < nz; ++z)
        s += pbuf[((size_t)z * NTRI + t) * 2048 + local];

    const int li = local >> 6;
    const int lj = (local >> 1) & 31;
    const int c  = local & 1;
    s += b2[c];

    const int i = bi * 32 + li;
    const int j = bj * 32 + lj;
    out[(i * LL + j) * 2 + c] = s;
    out[(j * LL + i) * 2 + c] = s;   // diagonal tiles: same-value rewrite, benign
}

extern "C" void kernel_launch(void* const* d_in, const int* in_sizes, int n_in,
                              void* d_out, int out_size, void* d_ws, size_t ws_size,
                              hipStream_t stream)
{
    const float* lm = (const float*)d_in[0];
    const float* W1 = (const float*)d_in[1];
    const float* b1 = (const float*)d_in[2];
    const float* W2 = (const float*)d_in[3];
    const float* b2 = (const float*)d_in[4];
    float* out = (float*)d_out;

    float* Ea   = (float*)d_ws;                            // 2 MB
    float* Eb   = Ea + (size_t)LL * HH;                    // 2 MB
    float* pbuf = Eb + (size_t)LL * HH;                    // nz * 1.11 MB

    // nz by available workspace (ws_size is constant per session -> graph-safe)
    const size_t base = (size_t)4 * LL * HH * 2;           // Ea+Eb bytes
    int nz = 8;
    while (nz > 1 && base + (size_t)nz * NTRI * 2048 * 4 > ws_size) nz >>= 1;

    proj_mfma_kernel<<<dim3(32, 32), 256, 0, stream>>>(lm, W1, b1, Ea, Eb);
    pair_kernel<<<dim3(NTRI, nz), 256, 0, stream>>>(Ea, Eb, W2, pbuf, nz);
    combine_kernel<<<(NTRI * 2048) / 256, 256, 0, stream>>>(pbuf, b2, out, nz);
}

// Round 6
// 130.780 us; speedup vs baseline: 1.2026x; 1.0480x over previous
//
#include <hip/hip_runtime.h>
#include <hip/hip_bf16.h>

#define HH 1024
#define LL 512
#define NT 16              // 512/32 row-tiles
#define NTRI 136           // NT*(NT+1)/2 triangular tiles

typedef __attribute__((ext_vector_type(8))) short bf16x8;
typedef __attribute__((ext_vector_type(4))) float f32x4;

static constexpr float C_EXP = 2.8853900817779268f; // 2*log2(e)

// pack 8 fp32 -> 8 bf16 (RNE) as uint4, element order preserved
static __device__ __forceinline__ uint4 pack8(float4 a, float4 b) {
    union { uint4 u; __hip_bfloat162 h[4]; } r;
    r.h[0] = __float22bfloat162_rn(make_float2(a.x, a.y));
    r.h[1] = __float22bfloat162_rn(make_float2(a.z, a.w));
    r.h[2] = __float22bfloat162_rn(make_float2(b.x, b.y));
    r.h[3] = __float22bfloat162_rn(make_float2(b.z, b.w));
    return r.u;
}

// ---------------------------------------------------------------------------
// Kernel 0: fp32->bf16 convert (lm 1MB, W1 4MB) + wsum[c] = sum_h W2[c,h].
//   B16[n][k] = bf16(W1[(n&1023)*2048 + (n>>10)*1024 + k])   n<1024: Wa, else Wb
// Grid 1281: blocks 0..1279 convert (8 elems/thread), block 1280 does wsum.
// ---------------------------------------------------------------------------
__global__ __launch_bounds__(256) void convert_kernel(
    const float* __restrict__ lm, const float* __restrict__ W1,
    const float* __restrict__ W2,
    ushort* __restrict__ lm16, ushort* __restrict__ B16, float* __restrict__ wsum)
{
    const int b = blockIdx.x;
    if (b == 1280) {
        const int tid = threadIdx.x;
        if (tid < 128) {
            const int c = tid >> 6, l = tid & 63;
            float s = 0.f;
            for (int q = l; q < 256; q += 64) {
                const float4 v = *(const float4*)&W2[c * HH + q * 4];
                s += v.x + v.y + v.z + v.w;
            }
#pragma unroll
            for (int off = 32; off; off >>= 1) s += __shfl_down(s, off, 64);
            if (l == 0) wsum[c] = s;
        }
        return;
    }
    const int q = b * 256 + threadIdx.x;            // 8-elem group, 0..327679
    if (q < 65536) {                                // lm: 512*1024/8
        const float4 a = *(const float4*)&lm[q * 8];
        const float4 c = *(const float4*)&lm[q * 8 + 4];
        ((uint4*)lm16)[q] = pack8(a, c);
    } else {
        const int p = q - 65536;                    // 0..262143
        const int n = p >> 7, k8 = (p & 127) * 8;
        const float* src = &W1[(n & 1023) * 2048 + (n >> 10) * 1024 + k8];
        ((uint4*)B16)[p] = pack8(*(const float4*)src, *(const float4*)(src + 4));
    }
}

// ---------------------------------------------------------------------------
// Kernel 1: bf16 MFMA projection from pre-converted inputs.
//   n < 1024:  Ea[m][n] = exp2(C*(acc + b1[n]));  else Eb[m][n-1024] = exp2(C*acc)
// Tile 16m x 64n, BK=128, 4 waves each own a 16-wide n-strip. Grid 1024 (1D).
// XCD swizzle: XCD = b&7 owns nbase in {4*XCD..4*XCD+3} for all 32 mbase ->
// per-XCD L2 working set = 1MB B16-slice + 1MB lm16: all re-reads are L2 hits.
// ---------------------------------------------------------------------------
__global__ __launch_bounds__(256, 4) void proj_mfma_kernel(
    const ushort* __restrict__ lm16, const ushort* __restrict__ B16,
    const float* __restrict__ b1, float* __restrict__ Ea, float* __restrict__ Eb)
{
    __shared__ ushort As[16][136];  // 136 us = 68 dw = 4 mod 32 banks: <=2-way, free
    __shared__ ushort Bs[64][136];

    const int tid  = threadIdx.x;
    const int lane = tid & 63;
    const int w    = tid >> 6;
    const int linear = blockIdx.x;
    const int xcd  = linear & 7;          // dispatch round-robin heuristic
    const int idx  = linear >> 3;         // 0..127 within XCD
    const int nbase = (xcd * 4 + (idx & 3)) * 64;
    const int mbase = (idx >> 2) * 16;
    const int wn   = w * 16;

    const int mrow = lane & 15;
    const int q8   = (lane >> 4) * 8;

    f32x4 acc = {0.f, 0.f, 0.f, 0.f};

    for (int kb = 0; kb < HH; kb += 128) {
        __syncthreads();
        {
            const int row = tid >> 4, c8 = (tid & 15) * 8;
            *(uint4*)&As[row][c8] = *(const uint4*)&lm16[(mbase + row) * HH + kb + c8];
            int p = tid;
#pragma unroll
            for (int it = 0; it < 4; ++it, p += 256) {
                const int br = p >> 4, bc8 = (p & 15) * 8;
                *(uint4*)&Bs[br][bc8] = *(const uint4*)&B16[(nbase + br) * HH + kb + bc8];
            }
        }
        __syncthreads();

#pragma unroll
        for (int s = 0; s < 4; ++s) {
            const bf16x8 a = *(const bf16x8*)&As[mrow][s * 32 + q8];
            const bf16x8 b = *(const bf16x8*)&Bs[wn + mrow][s * 32 + q8];
            acc = __builtin_amdgcn_mfma_f32_16x16x32_bf16(a, b, acc, 0, 0, 0);
        }
    }

    // D mapping: col=lane&15 (n within strip), row=(lane>>4)*4+reg (m)
    const int col = lane & 15;
    const int rq  = (lane >> 4) * 4;
    const int n_g = nbase + wn + col;
    const int m0  = mbase + rq;
    if (n_g < HH) {                       // uniform per block
        const float bb = b1[n_g];
#pragma unroll
        for (int r = 0; r < 4; ++r)
            Ea[(m0 + r) * HH + n_g] = __builtin_amdgcn_exp2f(C_EXP * (acc[r] + bb));
    } else {
#pragma unroll
        for (int r = 0; r < 4; ++r)
            Eb[(m0 + r) * HH + (n_g - HH)] = __builtin_amdgcn_exp2f(C_EXP * acc[r]);
    }
}

// ---------------------------------------------------------------------------
// Kernel 2: triangular pairwise contraction, symmetrization fused in-register.
//   u = 1/(Ea[j,h]*Eb[i,h]+1) + 1/(Ea[i,h]*Eb[j,h]+1)
//   pbuf = sum_slice u * W2[c,h]      (sign/constant folded into combine)
// Block = one (bi<=bj) 32x32 tile pair x one 64-h slice (nz=16: single K-iter,
// single barrier). Thread owns 2i x 2j. Plain stores, no atomics.
// ---------------------------------------------------------------------------
__global__ __launch_bounds__(256, 4) void pair_kernel(
    const float* __restrict__ Ea, const float* __restrict__ Eb,
    const float* __restrict__ W2, float* __restrict__ pbuf, int nz)
{
    __shared__ float eaj[32][68];   // stride 68 = 4 mod 32 banks: <=2-way, free
    __shared__ float eai[32][68];
    __shared__ float ebi[32][68];
    __shared__ float ebj[32][68];
    __shared__ float w0_s[256], w1_s[256];

    const int tid = threadIdx.x;
    const int tx  = tid & 15;
    const int ty  = tid >> 4;

    // triangular tile decode (uniform scalar loop)
    int tt = blockIdx.x, bi = 0, rem = NT;
    while (tt >= rem) { tt -= rem; --rem; ++bi; }
    const int bj    = bi + tt;
    const int ibase = bi * 32;
    const int jbase = bj * 32;
    const int slice = HH / nz;
    const int k0    = blockIdx.y * slice;

    // stage raw W2 slice
    if (tid < 128) {
        const int c = tid >> 6, l = tid & 63;
        float* ws = c ? w1_s : w0_s;
        for (int q = l; q < slice / 4; q += 64)
            ((float4*)ws)[q] = *(const float4*)&W2[c * HH + k0 + q * 4];
    }

    float acc[2][2][2] = {};  // [ii][jj][c]

    for (int kb = 0; kb < slice; kb += 64) {
        __syncthreads();
        {   // stage 4 tiles x 32 rows x 64 floats = 2048 float4, 8/thread
            int p = tid;
#pragma unroll
            for (int it = 0; it < 8; ++it, p += 256) {
                const int tile = p >> 9;
                const int row  = (p >> 4) & 31;
                const int c4   = p & 15;
                float4 v;
                if      (tile == 0) v = *(const float4*)&Ea[(jbase + row) * HH + k0 + kb + c4 * 4];
                else if (tile == 1) v = *(const float4*)&Ea[(ibase + row) * HH + k0 + kb + c4 * 4];
                else if (tile == 2) v = *(const float4*)&Eb[(ibase + row) * HH + k0 + kb + c4 * 4];
                else                v = *(const float4*)&Eb[(jbase + row) * HH + k0 + kb + c4 * 4];
                if      (tile == 0) *(float4*)&eaj[row][c4 * 4] = v;
                else if (tile == 1) *(float4*)&eai[row][c4 * 4] = v;
                else if (tile == 2) *(float4*)&ebi[row][c4 * 4] = v;
                else                *(float4*)&ebj[row][c4 * 4] = v;
            }
        }
        __syncthreads();

#pragma unroll 4
        for (int h4 = 0; h4 < 16; ++h4) {
            const float4 Aj0 = *(const float4*)&eaj[tx][h4 * 4];
            const float4 Aj1 = *(const float4*)&eaj[tx + 16][h4 * 4];
            const float4 Bi0 = *(const float4*)&ebi[ty][h4 * 4];
            const float4 Bi1 = *(const float4*)&ebi[ty + 16][h4 * 4];
            const float4 Ai0 = *(const float4*)&eai[ty][h4 * 4];
            const float4 Ai1 = *(const float4*)&eai[ty + 16][h4 * 4];
            const float4 Bj0 = *(const float4*)&ebj[tx][h4 * 4];
            const float4 Bj1 = *(const float4*)&ebj[tx + 16][h4 * 4];
            const float4 w0  = *(const float4*)&w0_s[kb + h4 * 4];  // broadcast
            const float4 w1  = *(const float4*)&w1_s[kb + h4 * 4];

#define DO_H(AJ0, AJ1, BI0, BI1, AI0, AI1, BJ0, BJ1, W0V, W1V)        \
            {                                                          \
                const float d00 = __builtin_fmaf((BI0), (AJ0), 1.f);   \
                const float d01 = __builtin_fmaf((BI0), (AJ1), 1.f);   \
                const float d10 = __builtin_fmaf((BI1), (AJ0), 1.f);   \
                const float d11 = __builtin_fmaf((BI1), (AJ1), 1.f);   \
                const float e00 = __builtin_fmaf((AI0), (BJ0), 1.f);   \
                const float e01 = __builtin_fmaf((AI0), (BJ1), 1.f);   \
                const float e10 = __builtin_fmaf((AI1), (BJ0), 1.f);   \
                const float e11 = __builtin_fmaf((AI1), (BJ1), 1.f);   \
                const float dp0 = d00 * d01, dp1 = d10 * d11;          \
                const float DR  = __builtin_amdgcn_rcpf(dp0 * dp1);    \
                const float dq0 = DR * dp1, dq1 = DR * dp0;            \
                const float rd00 = dq0 * d01, rd01 = dq0 * d00;        \
                const float rd10 = dq1 * d11, rd11 = dq1 * d10;        \
                const float ep0 = e00 * e01, ep1 = e10 * e11;          \
                const float ER  = __builtin_amdgcn_rcpf(ep0 * ep1);    \
                const float eq0 = ER * ep1, eq1 = ER * ep0;            \
                const float re00 = eq0 * e01, re01 = eq0 * e00;        \
                const float re10 = eq1 * e11, re11 = eq1 * e10;        \
                const float u00 = rd00 + re00, u01 = rd01 + re01;      \
                const float u10 = rd10 + re10, u11 = rd11 + re11;      \
                acc[0][0][0] = __builtin_fmaf(u00, (W0V), acc[0][0][0]); \
                acc[0][0][1] = __builtin_fmaf(u00, (W1V), acc[0][0][1]); \
                acc[0][1][0] = __builtin_fmaf(u01, (W0V), acc[0][1][0]); \
                acc[0][1][1] = __builtin_fmaf(u01, (W1V), acc[0][1][1]); \
                acc[1][0][0] = __builtin_fmaf(u10, (W0V), acc[1][0][0]); \
                acc[1][0][1] = __builtin_fmaf(u10, (W1V), acc[1][0][1]); \
                acc[1][1][0] = __builtin_fmaf(u11, (W0V), acc[1][1][0]); \
                acc[1][1][1] = __builtin_fmaf(u11, (W1V), acc[1][1][1]); \
            }
            DO_H(Aj0.x, Aj1.x, Bi0.x, Bi1.x, Ai0.x, Ai1.x, Bj0.x, Bj1.x, w0.x, w1.x)
            DO_H(Aj0.y, Aj1.y, Bi0.y, Bi1.y, Ai0.y, Ai1.y, Bj0.y, Bj1.y, w0.y, w1.y)
            DO_H(Aj0.z, Aj1.z, Bi0.z, Bi1.z, Ai0.z, Ai1.z, Bj0.z, Bj1.z, w0.z, w1.z)
            DO_H(Aj0.w, Aj1.w, Bi0.w, Bi1.w, Ai0.w, Ai1.w, Bj0.w, Bj1.w, w0.w, w1.w)
#undef DO_H
        }
    }

    float* pb = pbuf + ((size_t)blockIdx.y * NTRI + blockIdx.x) * 2048;
#pragma unroll
    for (int ii = 0; ii < 2; ++ii)
#pragma unroll
        for (int jj = 0; jj < 2; ++jj) {
            const int li = ty + ii * 16, lj = tx + jj * 16;
            *(float2*)&pb[(li * 32 + lj) * 2] =
                make_float2(acc[ii][jj][0], acc[ii][jj][1]);
        }
}

// ---------------------------------------------------------------------------
// Kernel 3: combine slice-partials: out = wsum[c] + b2[c] - sum_z pbuf,
// scatter to (i,j) and (j,i).
// ---------------------------------------------------------------------------
__global__ __launch_bounds__(256) void combine_kernel(
    const float* __restrict__ pbuf, const float* __restrict__ b2,
    const float* __restrict__ wsum, float* __restrict__ out, int nz)
{
    const int idx   = blockIdx.x * 256 + threadIdx.x;   // 0 .. 136*2048-1
    const int t     = idx >> 11;
    const int local = idx & 2047;
    int tt = t, bi = 0, rem = NT;
    while (tt >= rem) { tt -= rem; --rem; ++bi; }
    const int bj = bi + tt;

    float s = 0.f;
    for (int z = 0; z < nz; ++z)
        s += pbuf[((size_t)z * NTRI + t) * 2048 + local];

    const int li = local >> 6;
    const int lj = (local >> 1) & 31;
    const int c  = local & 1;
    const float v = wsum[c] + b2[c] - s;

    const int i = bi * 32 + li;
    const int j = bj * 32 + lj;
    out[(i * LL + j) * 2 + c] = v;
    out[(j * LL + i) * 2 + c] = v;   // diagonal tiles: same-value rewrite, benign
}

extern "C" void kernel_launch(void* const* d_in, const int* in_sizes, int n_in,
                              void* d_out, int out_size, void* d_ws, size_t ws_size,
                              hipStream_t stream)
{
    const float* lm = (const float*)d_in[0];
    const float* W1 = (const float*)d_in[1];
    const float* b1 = (const float*)d_in[2];
    const float* W2 = (const float*)d_in[3];
    const float* b2 = (const float*)d_in[4];
    float* out = (float*)d_out;

    char* ws = (char*)d_ws;
    float*  Ea   = (float*)ws;                           // 2 MB
    float*  Eb   = (float*)(ws + (2u << 20));            // 2 MB
    ushort* lm16 = (ushort*)(ws + (4u << 20));           // 1 MB
    ushort* B16  = (ushort*)(ws + (5u << 20));           // 4 MB
    float*  wsum = (float*)(ws + (9u << 20));            // 256 B
    float*  pbuf = (float*)(ws + (9u << 20) + 256);      // nz * 1.11 MB

    const size_t base = (9u << 20) + 256;
    int nz = 16;
    while (nz > 4 && base + (size_t)nz * NTRI * 2048 * 4 > ws_size) nz >>= 1;

    convert_kernel<<<1281, 256, 0, stream>>>(lm, W1, W2, lm16, B16, wsum);
    proj_mfma_kernel<<<1024, 256, 0, stream>>>(lm16, B16, b1, Ea, Eb);
    pair_kernel<<<dim3(NTRI, nz), 256, 0, stream>>>(Ea, Eb, W2, pbuf, nz);
    combine_kernel<<<(NTRI * 2048) / 256, 256, 0, stream>>>(pbuf, b2, wsum, out, nz);
}